// Round 3
// baseline (118.699 us; speedup 1.0000x reference)
//
#include <hip/hip_runtime.h>
#include <stdint.h>

#define NN 8192
#define KD 512
#define BM 128
#define BK 32
#define NTILE (NN / BM)                 // 64
#define NTRI (NTILE * (NTILE + 1) / 2)  // 2080

typedef __bf16 bf16;
typedef __bf16 bf16x8 __attribute__((ext_vector_type(8)));
typedef float f32x4 __attribute__((ext_vector_type(4)));

// ---------------- kernel 1: row L2-normalize, fp32 -> bf16 ----------------
__global__ __launch_bounds__(256) void rownorm_kernel(const float* __restrict__ proto,
                                                      bf16* __restrict__ pn) {
    const int row  = blockIdx.x * 4 + (threadIdx.x >> 6);
    const int lane = threadIdx.x & 63;
    const float4* src = (const float4*)(proto + (size_t)row * KD) + lane * 2;
    const float4 v0 = src[0];
    const float4 v1 = src[1];
    float s = v0.x*v0.x + v0.y*v0.y + v0.z*v0.z + v0.w*v0.w
            + v1.x*v1.x + v1.y*v1.y + v1.z*v1.z + v1.w*v1.w;
#pragma unroll
    for (int off = 32; off; off >>= 1) s += __shfl_xor(s, off);
    const float inv = 1.0f / fmaxf(sqrtf(s), 1e-12f);
    bf16x8 o;
    o[0] = (bf16)(v0.x*inv); o[1] = (bf16)(v0.y*inv);
    o[2] = (bf16)(v0.z*inv); o[3] = (bf16)(v0.w*inv);
    o[4] = (bf16)(v1.x*inv); o[5] = (bf16)(v1.y*inv);
    o[6] = (bf16)(v1.z*inv); o[7] = (bf16)(v1.w*inv);
    *(bf16x8*)(pn + (size_t)row * KD + lane * 8) = o;
}

// ------- kernel 2: C = leakyrelu(P P^T), symmetric, dbuf 2-phase ----------
__device__ __forceinline__ void gload_lds16(const bf16* g, bf16* l) {
    __builtin_amdgcn_global_load_lds(
        (const __attribute__((address_space(1))) void*)g,
        (__attribute__((address_space(3))) void*)l, 16, 0, 0);
}

__device__ __forceinline__ float lrelu(float v) {
    return (v >= 0.0f) ? v : 0.01f * v;
}

__global__ __launch_bounds__(256) void gemm_sym_kernel(const bf16* __restrict__ P,
                                                       float* __restrict__ C) {
    __shared__ bf16 sA[2][BM][BK];
    __shared__ bf16 sB[2][BM][BK];

    // bijective XCD swizzle: 2080 = 8 x 260
    const int bid = blockIdx.x;
    const int swz = (bid & 7) * (NTRI / 8) + (bid >> 3);
    int tm = 0, rem = swz;
    while (rem >= NTILE - tm) { rem -= NTILE - tm; ++tm; }
    const int tn = tm + rem;

    const int tid  = threadIdx.x;
    const int w    = tid >> 6;
    const int lane = tid & 63;
    const int rowA0 = tm * BM;
    const int rowB0 = tn * BM;
    const int wm = (w >> 1) * 64;
    const int wn = (w & 1) * 64;
    const int rsel  = lane & 15;
    const int khalf = (lane >> 4) * 8;

    // staging geometry (hoisted): wave w owns 16B chunks [w*128 .. w*128+127]
    const int chunk0 = (w * 2) * 64 + lane;      // slot 0
    const int chunk1 = (w * 2 + 1) * 64 + lane;  // slot 1
    const bf16* gA0 = P + (size_t)(rowA0 + (chunk0 >> 2)) * KD + (chunk0 & 3) * 8;
    const bf16* gA1 = P + (size_t)(rowA0 + (chunk1 >> 2)) * KD + (chunk1 & 3) * 8;
    const bf16* gB0 = P + (size_t)(rowB0 + (chunk0 >> 2)) * KD + (chunk0 & 3) * 8;
    const bf16* gB1 = P + (size_t)(rowB0 + (chunk1 >> 2)) * KD + (chunk1 & 3) * 8;
    const int ldsOff0 = (w * 2 + 0) * 512;   // element offset of 1KB slot 0
    const int ldsOff1 = (w * 2 + 1) * 512;   // element offset of 1KB slot 1

    f32x4 acc[4][4] = {};

#define STAGE(buf, kt)                                          \
    do {                                                        \
        gload_lds16(gA0 + (kt), &sA[buf][0][0] + ldsOff0);      \
        gload_lds16(gA1 + (kt), &sA[buf][0][0] + ldsOff1);      \
        gload_lds16(gB0 + (kt), &sB[buf][0][0] + ldsOff0);      \
        gload_lds16(gB1 + (kt), &sB[buf][0][0] + ldsOff1);      \
    } while (0)

#define COMPUTE(buf)                                                        \
    do {                                                                    \
        bf16x8 af[4], bfr[4];                                               \
        _Pragma("unroll")                                                   \
        for (int m = 0; m < 4; ++m)                                         \
            af[m] = *(const bf16x8*)&sA[buf][wm + m * 16 + rsel][khalf];    \
        _Pragma("unroll")                                                   \
        for (int n = 0; n < 4; ++n)                                         \
            bfr[n] = *(const bf16x8*)&sB[buf][wn + n * 16 + rsel][khalf];   \
        _Pragma("unroll")                                                   \
        for (int m = 0; m < 4; ++m)                                         \
            _Pragma("unroll")                                               \
            for (int n = 0; n < 4; ++n)                                     \
                acc[m][n] = __builtin_amdgcn_mfma_f32_16x16x32_bf16(        \
                    af[m], bfr[n], acc[m][n], 0, 0, 0);                     \
    } while (0)

    // prologue: tile 0 -> buf 0
    STAGE(0, 0);
    __syncthreads();                       // vmcnt(0) drain + barrier

    // 16 K-tiles total; stage t+1 into buf^1 BEFORE computing t from buf
#pragma unroll 1
    for (int t = 0; t < 14; t += 2) {
        STAGE(1, (t + 1) * BK);
        COMPUTE(0);
        __syncthreads();
        STAGE(0, (t + 2) * BK);
        COMPUTE(1);
        __syncthreads();
    }
    STAGE(1, 15 * BK);
    COMPUTE(0);                            // tile 14
    __syncthreads();
    COMPUTE(1);                            // tile 15

    const int cr = (lane >> 4) * 4;   // acc reg r -> row cr+r
    const int cc = lane & 15;         // col

    // direct tile: C[rowA0 + ..][rowB0 + ..]
#pragma unroll
    for (int m = 0; m < 4; ++m)
#pragma unroll
        for (int n = 0; n < 4; ++n)
#pragma unroll
            for (int r = 0; r < 4; ++r)
                C[(size_t)(rowA0 + wm + m * 16 + cr + r) * NN
                  + (rowB0 + wn + n * 16 + cc)] = lrelu(acc[m][n][r]);

    // mirror tile (off-diagonal only): per-lane float4 rows of C^T
    if (tm != tn) {
#pragma unroll
        for (int m = 0; m < 4; ++m)
#pragma unroll
            for (int n = 0; n < 4; ++n) {
                float4 vv;
                vv.x = lrelu(acc[m][n][0]);
                vv.y = lrelu(acc[m][n][1]);
                vv.z = lrelu(acc[m][n][2]);
                vv.w = lrelu(acc[m][n][3]);
                *(float4*)&C[(size_t)(rowB0 + wn + n * 16 + cc) * NN
                             + (rowA0 + wm + m * 16 + cr)] = vv;
            }
    }
#undef STAGE
#undef COMPUTE
}

extern "C" void kernel_launch(void* const* d_in, const int* in_sizes, int n_in,
                              void* d_out, int out_size, void* d_ws, size_t ws_size,
                              hipStream_t stream) {
    const float* proto = (const float*)d_in[1];
    float* C  = (float*)d_out;
    bf16* pn  = (bf16*)d_ws;   // 8 MB scratch

    rownorm_kernel<<<dim3(NN / 4), dim3(256), 0, stream>>>(proto, pn);
    gemm_sym_kernel<<<dim3(NTRI), dim3(256), 0, stream>>>(pn, C);
}

// Round 4
// 101.726 us; speedup vs baseline: 1.1668x; 1.1668x over previous
//
#include <hip/hip_runtime.h>
#include <stdint.h>

#define NN 8192
#define KD 512
#define BM 128
#define BK 32
#define NTILE (NN / BM)                 // 64
#define NTRI (NTILE * (NTILE + 1) / 2)  // 2080
#define NKT (KD / BK)                   // 16

typedef __bf16 bf16;
typedef __bf16 bf16x8 __attribute__((ext_vector_type(8)));
typedef float f32x4 __attribute__((ext_vector_type(4)));

// ---------------- kernel 1: row L2-normalize, fp32 -> bf16 ----------------
__global__ __launch_bounds__(256) void rownorm_kernel(const float* __restrict__ proto,
                                                      bf16* __restrict__ pn) {
    const int row  = blockIdx.x * 4 + (threadIdx.x >> 6);
    const int lane = threadIdx.x & 63;
    const float4* src = (const float4*)(proto + (size_t)row * KD) + lane * 2;
    const float4 v0 = src[0];
    const float4 v1 = src[1];
    float s = v0.x*v0.x + v0.y*v0.y + v0.z*v0.z + v0.w*v0.w
            + v1.x*v1.x + v1.y*v1.y + v1.z*v1.z + v1.w*v1.w;
#pragma unroll
    for (int off = 32; off; off >>= 1) s += __shfl_xor(s, off);
    const float inv = 1.0f / fmaxf(sqrtf(s), 1e-12f);
    bf16x8 o;
    o[0] = (bf16)(v0.x*inv); o[1] = (bf16)(v0.y*inv);
    o[2] = (bf16)(v0.z*inv); o[3] = (bf16)(v0.w*inv);
    o[4] = (bf16)(v1.x*inv); o[5] = (bf16)(v1.y*inv);
    o[6] = (bf16)(v1.z*inv); o[7] = (bf16)(v1.w*inv);
    *(bf16x8*)(pn + (size_t)row * KD + lane * 8) = o;
}

// ------- kernel 2: C = leakyrelu(P P^T), symmetric, dbuf, 4 blocks/CU -----
__device__ __forceinline__ void gload_lds16(const bf16* g, bf16* l) {
    __builtin_amdgcn_global_load_lds(
        (const __attribute__((address_space(1))) void*)g,
        (__attribute__((address_space(3))) void*)l, 16, 0, 0);
}

__device__ __forceinline__ float lrelu(float v) {
    return (v >= 0.0f) ? v : 0.01f * v;
}

__global__ __launch_bounds__(256, 4) void gemm_sym_kernel(const bf16* __restrict__ P,
                                                          float* __restrict__ C) {
    __shared__ bf16 sA[2][BM][BK];
    __shared__ bf16 sB[2][BM][BK];

    // bijective XCD swizzle: 2080 = 8 x 260
    const int bid = blockIdx.x;
    const int swz = (bid & 7) * (NTRI / 8) + (bid >> 3);
    int tm = 0, rem = swz;
    while (rem >= NTILE - tm) { rem -= NTILE - tm; ++tm; }
    const int tn = tm + rem;

    const int tid  = threadIdx.x;
    const int w    = tid >> 6;
    const int lane = tid & 63;
    const int rowA0 = tm * BM;
    const int rowB0 = tn * BM;
    const int wm = (w >> 1) * 64;
    const int wn = (w & 1) * 64;
    const int rsel  = lane & 15;
    const int khalf = (lane >> 4) * 8;

    // staging geometry: one per-lane base + wave-uniform offsets (VGPR diet)
    const int chunk0 = w * 128 + lane;                 // 16B-chunk id, slot 0
    const bf16* g0 = P + (size_t)(chunk0 >> 2) * KD + (chunk0 & 3) * 8;
    const size_t offA = (size_t)rowA0 * KD;
    const size_t offB = (size_t)rowB0 * KD;
    const int ldsOff0 = w * 1024;            // elements: slot0 of wave w
    const int ldsOff1 = w * 1024 + 512;      // slot1 (+16 rows -> +16*KD global)

    f32x4 acc[4][4] = {};

#define STAGE(buf, kt)                                                  \
    do {                                                                \
        gload_lds16(g0 + offA + (kt),           &sA[buf][0][0] + ldsOff0); \
        gload_lds16(g0 + offA + 16 * KD + (kt), &sA[buf][0][0] + ldsOff1); \
        gload_lds16(g0 + offB + (kt),           &sB[buf][0][0] + ldsOff0); \
        gload_lds16(g0 + offB + 16 * KD + (kt), &sB[buf][0][0] + ldsOff1); \
    } while (0)

#define COMPUTE(buf)                                                        \
    do {                                                                    \
        bf16x8 af[4], bfr[4];                                               \
        _Pragma("unroll")                                                   \
        for (int m = 0; m < 4; ++m)                                         \
            af[m] = *(const bf16x8*)&sA[buf][wm + m * 16 + rsel][khalf];    \
        _Pragma("unroll")                                                   \
        for (int n = 0; n < 4; ++n)                                         \
            bfr[n] = *(const bf16x8*)&sB[buf][wn + n * 16 + rsel][khalf];   \
        _Pragma("unroll")                                                   \
        for (int m = 0; m < 4; ++m)                                         \
            _Pragma("unroll")                                               \
            for (int n = 0; n < 4; ++n)                                     \
                acc[m][n] = __builtin_amdgcn_mfma_f32_16x16x32_bf16(        \
                    af[m], bfr[n], acc[m][n], 0, 0, 0);                     \
    } while (0)

    // prologue: tile 0 -> buf 0
    STAGE(0, 0);
    __syncthreads();

    // fully unrolled: stage t+1 (buf parity compile-time, offset = imm),
    // compute t, one barrier per K-tile
#pragma unroll
    for (int t = 0; t < NKT; ++t) {
        if (t < NKT - 1) STAGE((t + 1) & 1, (t + 1) * BK);
        COMPUTE(t & 1);
        if (t < NKT - 1) __syncthreads();
    }

    const int cr = (lane >> 4) * 4;   // acc reg r -> row cr+r
    const int cc = lane & 15;         // col

    // direct tile: C[rowA0 + ..][rowB0 + ..]
#pragma unroll
    for (int m = 0; m < 4; ++m)
#pragma unroll
        for (int n = 0; n < 4; ++n)
#pragma unroll
            for (int r = 0; r < 4; ++r)
                C[(size_t)(rowA0 + wm + m * 16 + cr + r) * NN
                  + (rowB0 + wn + n * 16 + cc)] = lrelu(acc[m][n][r]);

    // mirror tile (off-diagonal only): per-lane float4 rows of C^T
    if (tm != tn) {
#pragma unroll
        for (int m = 0; m < 4; ++m)
#pragma unroll
            for (int n = 0; n < 4; ++n) {
                float4 vv;
                vv.x = lrelu(acc[m][n][0]);
                vv.y = lrelu(acc[m][n][1]);
                vv.z = lrelu(acc[m][n][2]);
                vv.w = lrelu(acc[m][n][3]);
                *(float4*)&C[(size_t)(rowB0 + wn + n * 16 + cc) * NN
                             + (rowA0 + wm + m * 16 + cr)] = vv;
            }
    }
#undef STAGE
#undef COMPUTE
}

extern "C" void kernel_launch(void* const* d_in, const int* in_sizes, int n_in,
                              void* d_out, int out_size, void* d_ws, size_t ws_size,
                              hipStream_t stream) {
    const float* proto = (const float*)d_in[1];
    float* C  = (float*)d_out;
    bf16* pn  = (bf16*)d_ws;   // 8 MB scratch

    rownorm_kernel<<<dim3(NN / 4), dim3(256), 0, stream>>>(proto, pn);
    gemm_sym_kernel<<<dim3(NTRI), dim3(256), 0, stream>>>(pn, C);
}